// Round 3
// baseline (478.365 us; speedup 1.0000x reference)
//
#include <hip/hip_runtime.h>
#include <hip/hip_bf16.h>

#define T_LEN   100000   // time samples
#define C_SEL   256      // selected channels
#define C_IN    512      // input channel stride
#define KLOW    12000    // low-pass taps
#define B1      50       // low-pass decimation block
#define NB1     2000     // T_LEN / B1
#define ND1     2001     // low nodes: t = 50*jd, jd = 0..2000
#define NW1     241      // block-averaged low weights
#define ND2E    5003     // out nodes: t = 20*(jo-1), jo = 0..5002 (one extra each side for Catmull-Rom)
#define WH_OFF  5500     // gauss_high truncation start (center 6000 ± 500)
#define KH      1001     // truncated high-pass taps

// k0: block-AVERAGED weights of the low-pass kernel (+ zero the mean accumulator).
// low[t] = sum_k w[k] x[t+k-5999]; with t=50*jd, input block jb aligns to
// w-range [50*m1-1, 50*m1+48], m1 = jb-jd+120 (since 5999 = 50*120 - 1).
// Contribution of block jb ≈ mean(w over block) * sum(x over block) = (Σw/50)*S.
__global__ __launch_bounds__(256) void k0_prep(const float* __restrict__ wlow,
                                               float* __restrict__ W1,
                                               float* __restrict__ musum){
  int m1 = threadIdx.x;
  if (m1 == 0) musum[0] = 0.f;
  if (m1 < NW1){
    float s = 0.f;
    int kbase = 50*m1 - 1;
    for (int off = 0; off < 50; ++off){
      int k = kbase + off;
      if (k >= 0 && k < KLOW) s += wlow[k];
    }
    W1[m1] = s * (1.0f/50.0f);   // FIX: block MEAN weight × block SUM of x (was 50× too big)
  }
}

// k1: 50-sample block sums of sel per channel. S[jb][c]
__global__ __launch_bounds__(256) void k1_bsum(const float* __restrict__ x,
                                               const int* __restrict__ sel,
                                               float* __restrict__ S){
  int jb = blockIdx.x, c = threadIdx.x;
  int sc = sel[c];
  const float* p = x + (size_t)jb*(B1*C_IN) + sc;
  float s = 0.f;
  #pragma unroll
  for (int i = 0; i < B1; ++i) s += p[(size_t)i*C_IN];
  S[jb*C_SEL + c] = s;
}

// k2: decimated low-pass: lowd[jd][c] = sum_m1 W1[m1]*S[jd+m1-120][c];
// fused: accumulate trapezoid-weighted sum for mean(low_full).
__global__ __launch_bounds__(256) void k2_lowd(const float* __restrict__ S,
                                               const float* __restrict__ W1,
                                               float* __restrict__ lowd,
                                               float* __restrict__ musum){
  __shared__ float w1s[NW1];
  __shared__ float red[256];
  int jd = blockIdx.x, c = threadIdx.x;
  if (c < NW1) w1s[c] = W1[c];
  __syncthreads();
  float acc = 0.f;
  for (int m1 = 0; m1 < NW1; ++m1){
    int jb = jd + m1 - 120;
    if (jb >= 0 && jb < NB1) acc += w1s[m1]*S[jb*C_SEL + c];
  }
  lowd[jd*C_SEL + c] = acc;
  red[c] = acc;
  __syncthreads();
  for (int s2 = 128; s2 > 0; s2 >>= 1){
    if (c < s2) red[c] += red[c + s2];
    __syncthreads();
  }
  if (c == 0){
    // sum_t lerp(low)[t] = 25.5*L[0] + 50*L[1..1999] + 24.5*L[2000]
    float ew = (jd == 0) ? 25.5f : ((jd == ND1-1) ? 24.5f : 50.f);
    atomicAdd(musum, ew*red[0]);
  }
}

// k3: filt = sel - lerp(lowd) + mu, staged as fp32 into d_out.
__global__ __launch_bounds__(256) void k3_filt(const float* __restrict__ x,
                                               const int* __restrict__ sel,
                                               const float* __restrict__ lowd,
                                               const float* __restrict__ musum,
                                               float* __restrict__ filt){
  int c = threadIdx.x;
  int sc = sel[c];
  float mu = musum[0] * (1.0f/((float)T_LEN*(float)C_SEL));
  int t0 = blockIdx.x*8;
  #pragma unroll
  for (int i = 0; i < 8; ++i){
    int t = t0 + i;
    int jd = t/50, rr = t - jd*50;
    float fr = rr*(1.f/50.f);
    float l0 = lowd[jd*C_SEL + c], l1 = lowd[(jd+1)*C_SEL + c];
    float lo = l0 + (l1 - l0)*fr;
    float v = x[(size_t)t*C_IN + sc];
    filt[(size_t)t*C_SEL + c] = v - lo + mu;
  }
}

// k4 core: 8 decimated outputs per thread, phase-decomposed so the 51
// weights per phase live in registers (const-indexed after full unroll).
// out_d[jo] = sum_{j=0..1000} whT[j]*filt[20*(jo-1) + j - 499]
template<bool FAST>
__device__ __forceinline__ void conv_core(const float* __restrict__ base,
                                          const float* __restrict__ whs,
                                          int tb, float* acc){
  #pragma unroll 1
  for (int p = 0; p < 20; ++p){
    float wp[51];
    #pragma unroll
    for (int u = 0; u < 51; ++u) wp[u] = whs[20*u + p];   // whs zero-padded to 1024
    #pragma unroll
    for (int q = 0; q < 58; ++q){
      int t = tb + 20*q + p;
      float v;
      if (FAST){
        v = base[(size_t)t*C_SEL];
      } else {
        v = (t >= 0 && t < T_LEN) ? base[(size_t)t*C_SEL] : 0.f;
      }
      #pragma unroll
      for (int r = 0; r < 8; ++r){
        int u = q - r;
        if (u >= 0 && u <= 50) acc[r] += wp[u]*v;
      }
    }
  }
}

__global__ __launch_bounds__(256) void k4_conv(const float* __restrict__ filt,
                                               const float* __restrict__ whigh,
                                               float* __restrict__ outd){
  __shared__ float whs[1024];
  int tid = threadIdx.x;
  for (int j = tid; j < 1024; j += 256)
    whs[j] = (j < KH) ? whigh[WH_OFF + j] : 0.f;
  __syncthreads();
  int c   = (blockIdx.y << 6) + (tid & 63);
  int g   = tid >> 6;
  int jo0 = blockIdx.x*32 + g*8;          // extended node index
  int tb  = 20*(jo0 - 1) - 499;
  float acc[8] = {0,0,0,0,0,0,0,0};
  const float* base = filt + c;
  if (tb >= 0 && tb + 1159 < T_LEN) conv_core<true >(base, whs, tb, acc);
  else                              conv_core<false>(base, whs, tb, acc);
  #pragma unroll
  for (int r = 0; r < 8; ++r){
    int jo = jo0 + r;
    if (jo < ND2E) outd[jo*C_SEL + c] = acc[r];
  }
}

// k5: Catmull-Rom interpolation of the decimated output back to full rate.
__global__ __launch_bounds__(256) void k5_interp(const float* __restrict__ outd,
                                                 float* __restrict__ out){
  int c = threadIdx.x;
  int t0 = blockIdx.x*8;
  #pragma unroll
  for (int i = 0; i < 8; ++i){
    int t = t0 + i;
    int jo = t/20, rr = t - jo*20;
    float a = rr*(1.f/20.f);
    float p0 = outd[(jo    )*C_SEL + c];
    float p1 = outd[(jo + 1)*C_SEL + c];   // node at t = 20*jo
    float p2 = outd[(jo + 2)*C_SEL + c];   // node at t = 20*(jo+1)
    float p3 = outd[(jo + 3)*C_SEL + c];
    float m = p1 + 0.5f*a*((p2 - p0)
            + a*((2.f*p0 - 5.f*p1 + 4.f*p2 - p3)
            + a*(3.f*(p1 - p2) + p3 - p0)));
    out[(size_t)t*C_SEL + c] = m;
  }
}

extern "C" void kernel_launch(void* const* d_in, const int* in_sizes, int n_in,
                              void* d_out, int out_size, void* d_ws, size_t ws_size,
                              hipStream_t stream){
  const float* firings = (const float*)d_in[0];
  const float* glow    = (const float*)d_in[1];
  const float* ghigh   = (const float*)d_in[2];
  const int*   sel     = (const int*)d_in[3];
  float* out = (float*)d_out;
  float* ws  = (float*)d_ws;

  // workspace layout (floats): ~9.2 MB total
  float* W1    = ws;                       // 256
  float* musum = ws + 256;                 // 64 (1 used)
  float* S     = ws + 320;                 // 2000*256 = 512000
  float* lowd  = ws + 320 + 512000;        // 2001*256 = 512256   (ends 1024576)
  float* outd  = ws + 1024640;             // 5003*256 = 1280768  (ends 2305408)
  float* filt  = out;                      // stage filt (fp32) in d_out; overwritten by k5

  hipLaunchKernelGGL(k0_prep,  dim3(1),        dim3(256), 0, stream, glow, W1, musum);
  hipLaunchKernelGGL(k1_bsum,  dim3(NB1),      dim3(256), 0, stream, firings, sel, S);
  hipLaunchKernelGGL(k2_lowd,  dim3(ND1),      dim3(256), 0, stream, S, W1, lowd, musum);
  hipLaunchKernelGGL(k3_filt,  dim3(T_LEN/8),  dim3(256), 0, stream, firings, sel, lowd, musum, filt);
  hipLaunchKernelGGL(k4_conv,  dim3(157, 4),   dim3(256), 0, stream, filt, ghigh, outd);
  hipLaunchKernelGGL(k5_interp,dim3(T_LEN/8),  dim3(256), 0, stream, outd, out);
}

// Round 4
// 477.913 us; speedup vs baseline: 1.0009x; 1.0009x over previous
//
#include <hip/hip_runtime.h>
#include <hip/hip_bf16.h>

#define T_LEN   100000   // time samples
#define C_SEL   256      // selected channels
#define C_IN    512      // input channel stride
#define KLOW    12000    // low-pass taps
#define B1      50       // low-pass decimation block
#define NB1     2000     // T_LEN / B1
#define ND1     2001     // low nodes: t = 50*jd, jd = 0..2000
#define NW1     241      // block-averaged low weights
#define ND2E    5003     // out nodes: t = 20*(jo-1), jo = 0..5002 (one extra each side for Catmull-Rom)
#define WH_OFF  5500     // gauss_high truncation start (center 6000 ± 500)
#define KH      1001     // truncated high-pass taps
#define NR      16       // decimated outputs per thread in kC
#define NBX     79       // ceil(5003 / (4 waves * 16 nodes))

// kA: fused prep + block sums.
//  blocks 0..NB1-1: S[jb][c] = 50-sample block sums of selected channels.
//  block NB1: W1 (block-averaged low weights), musum=0, cwh = prefix of truncated high kernel.
// low[t] = sum_k w[k] x[t+k-5999]; with t=50*jd, input block jb aligns to
// w-range [50*m1-1, 50*m1+48], m1 = jb-jd+120. Block contribution ≈ (Σw/50)*S.
__global__ __launch_bounds__(256) void kA_prep(const float* __restrict__ x,
                                               const int* __restrict__ sel,
                                               const float* __restrict__ wlow,
                                               const float* __restrict__ whigh,
                                               float* __restrict__ S,
                                               float* __restrict__ W1,
                                               float* __restrict__ musum,
                                               float* __restrict__ cwh){
  if (blockIdx.x < NB1){
    int jb = blockIdx.x, c = threadIdx.x;
    int sc = sel[c];
    const float* p = x + (size_t)jb*(B1*C_IN) + sc;
    float s = 0.f;
    #pragma unroll
    for (int i = 0; i < B1; ++i) s += p[(size_t)i*C_IN];
    S[jb*C_SEL + c] = s;
  } else {
    int m1 = threadIdx.x;
    if (m1 == 0){
      musum[0] = 0.f;
      float run = 0.f;
      cwh[0] = 0.f;
      for (int j = 0; j < KH; ++j){ run += whigh[WH_OFF + j]; cwh[j+1] = run; }
    }
    if (m1 < NW1){
      float s = 0.f;
      int kbase = 50*m1 - 1;
      for (int off = 0; off < 50; ++off){
        int k = kbase + off;
        if (k >= 0 && k < KLOW) s += wlow[k];
      }
      W1[m1] = s * (1.0f/50.0f);   // block MEAN weight × block SUM of x
    }
  }
}

// kB: decimated low-pass: lowd[jd][c] = sum_m1 W1[m1]*S[jd+m1-120][c];
// fused: trapezoid-weighted sum for mean(low_full) -> musum.
__global__ __launch_bounds__(256) void kB_lowd(const float* __restrict__ S,
                                               const float* __restrict__ W1,
                                               float* __restrict__ lowd,
                                               float* __restrict__ musum){
  __shared__ float w1s[NW1];
  __shared__ float red[256];
  int jd = blockIdx.x, c = threadIdx.x;
  if (c < NW1) w1s[c] = W1[c];
  __syncthreads();
  float acc = 0.f;
  for (int m1 = 0; m1 < NW1; ++m1){
    int jb = jd + m1 - 120;
    if (jb >= 0 && jb < NB1) acc += w1s[m1]*S[jb*C_SEL + c];
  }
  lowd[jd*C_SEL + c] = acc;
  red[c] = acc;
  __syncthreads();
  for (int s2 = 128; s2 > 0; s2 >>= 1){
    if (c < s2) red[c] += red[c + s2];
    __syncthreads();
  }
  if (c == 0){
    // sum_t lerp(low)[t] = 25.5*L[0] + 50*L[1..1999] + 24.5*L[2000]
    float ew = (jd == 0) ? 25.5f : ((jd == ND1-1) ? 24.5f : 50.f);
    atomicAdd(musum, ew*red[0]);
  }
}

// kC core: NR decimated outputs per thread, phase-decomposed; 51 weights/phase
// in registers (const-indexed after full unroll). Convolves RAW x (zero-padded):
// conv[jo] = sum_{j=0..1000} whT[j] * x_sel[20*(jo-1) + j - 499]
template<bool FAST>
__device__ __forceinline__ void conv_core(const float* __restrict__ base,
                                          const float* __restrict__ whs,
                                          int tb, float* acc){
  #pragma unroll 1
  for (int p = 0; p < 20; ++p){
    float wp[51];
    #pragma unroll
    for (int u = 0; u < 51; ++u) wp[u] = whs[20*u + p];   // whs zero-padded to 1024
    #pragma unroll
    for (int q = 0; q < NR + 50; ++q){
      int t = tb + 20*q + p;
      float v;
      if (FAST){
        v = base[(size_t)t*C_IN];
      } else {
        v = (t >= 0 && t < T_LEN) ? base[(size_t)t*C_IN] : 0.f;
      }
      #pragma unroll
      for (int r = 0; r < NR; ++r){
        int u = q - r;
        if (u >= 0 && u <= 50) acc[r] += wp[u]*v;
      }
    }
  }
}

// kC: outd[jo] = conv(x)[jo] + (mu - low(t_jo)) * s(t_jo)
// where s = valid-window mass of the truncated kernel (exact zero-pad edge
// handling) and low(t) ~ lerp(lowd) (G_high barely changes low: sigma ratio 20x).
__global__ __launch_bounds__(256) void kC_conv(const float* __restrict__ x,
                                               const int* __restrict__ sel,
                                               const float* __restrict__ whigh,
                                               const float* __restrict__ cwh,
                                               const float* __restrict__ lowd,
                                               const float* __restrict__ musum,
                                               float* __restrict__ outd){
  __shared__ float whs[1024];
  int tid = threadIdx.x;
  for (int j = tid; j < 1024; j += 256)
    whs[j] = (j < KH) ? whigh[WH_OFF + j] : 0.f;
  __syncthreads();
  int c  = (blockIdx.y << 6) + (tid & 63);
  int sc = sel[c];
  int g  = tid >> 6;
  int jo0 = blockIdx.x*(4*NR) + g*NR;     // extended node index
  int tb  = 20*(jo0 - 1) - 499;
  float acc[NR];
  #pragma unroll
  for (int r = 0; r < NR; ++r) acc[r] = 0.f;
  const float* base = x + sc;
  if (tb >= 0 && tb + 20*(NR+49) + 19 < T_LEN) conv_core<true >(base, whs, tb, acc);
  else                                         conv_core<false>(base, whs, tb, acc);

  float mu = musum[0] * (1.0f/((float)T_LEN*(float)C_SEL));
  #pragma unroll
  for (int r = 0; r < NR; ++r){
    int jo = jo0 + r;
    if (jo < ND2E){
      int tn = 20*(jo - 1);
      int jmin = 499 - tn;        if (jmin < 0) jmin = 0;
      int jmax = T_LEN - 1 + 499 - tn; if (jmax > 1000) jmax = 1000;
      float s = cwh[jmax + 1] - cwh[jmin];
      int tc = tn < 0 ? 0 : (tn > T_LEN-1 ? T_LEN-1 : tn);
      int jd = tc/50, rr = tc - 50*jd;
      float l0 = lowd[jd*C_SEL + c], l1 = lowd[(jd+1)*C_SEL + c];
      float lo = l0 + (l1 - l0)*(rr*(1.f/50.f));
      outd[jo*C_SEL + c] = acc[r] + (mu - lo)*s;
    }
  }
}

// kD: Catmull-Rom interpolation of the decimated output back to full rate.
__global__ __launch_bounds__(256) void kD_interp(const float* __restrict__ outd,
                                                 float* __restrict__ out){
  int c = threadIdx.x;
  int t0 = blockIdx.x*8;
  #pragma unroll
  for (int i = 0; i < 8; ++i){
    int t = t0 + i;
    int jo = t/20, rr = t - jo*20;
    float a = rr*(1.f/20.f);
    float p0 = outd[(jo    )*C_SEL + c];
    float p1 = outd[(jo + 1)*C_SEL + c];   // node at t = 20*jo
    float p2 = outd[(jo + 2)*C_SEL + c];   // node at t = 20*(jo+1)
    float p3 = outd[(jo + 3)*C_SEL + c];
    float m = p1 + 0.5f*a*((p2 - p0)
            + a*((2.f*p0 - 5.f*p1 + 4.f*p2 - p3)
            + a*(3.f*(p1 - p2) + p3 - p0)));
    out[(size_t)t*C_SEL + c] = m;
  }
}

extern "C" void kernel_launch(void* const* d_in, const int* in_sizes, int n_in,
                              void* d_out, int out_size, void* d_ws, size_t ws_size,
                              hipStream_t stream){
  const float* firings = (const float*)d_in[0];
  const float* glow    = (const float*)d_in[1];
  const float* ghigh   = (const float*)d_in[2];
  const int*   sel     = (const int*)d_in[3];
  float* out = (float*)d_out;
  float* ws  = (float*)d_ws;

  // workspace layout (floats): ~9.3 MB total
  float* W1    = ws;                 // 256
  float* musum = ws + 256;           // 64 (1 used)
  float* cwh   = ws + 320;           // 1002 (pad to 1728)
  float* S     = ws + 2048;          // 2000*256 = 512000   (ends 514048)
  float* lowd  = ws + 514048;        // 2001*256 = 512256   (ends 1026304)
  float* outd  = ws + 1026304;       // 5003*256 = 1280768  (ends 2307072)

  hipLaunchKernelGGL(kA_prep,  dim3(NB1+1),   dim3(256), 0, stream,
                     firings, sel, glow, ghigh, S, W1, musum, cwh);
  hipLaunchKernelGGL(kB_lowd,  dim3(ND1),     dim3(256), 0, stream, S, W1, lowd, musum);
  hipLaunchKernelGGL(kC_conv,  dim3(NBX, 4),  dim3(256), 0, stream,
                     firings, sel, ghigh, cwh, lowd, musum, outd);
  hipLaunchKernelGGL(kD_interp,dim3(T_LEN/8), dim3(256), 0, stream, outd, out);
}